// Round 2
// baseline (65.557 us; speedup 1.0000x reference)
//
#include <hip/hip_runtime.h>

// ZNCC 5x5, zero-padded, count_include_pad means.
// x,y: (4,3,512,512) f32 -> out: (4,1,512,512) f32
// Round 2: single-pass LDS read into regs (means + ncc from regs),
// global_load_lds staging for interior blocks, channel double-buffering.

constexpr int W  = 512, H = 512, C = 3, NB = 4;
constexpr int TW = 64, TH = 16, HALO = 2;
constexpr int LW = TW + 2 * HALO;   // 68 floats/row; 272B = 17*16 -> float4-aligned rows
constexpr int LH = TH + 2 * HALO;   // 20
constexpr int LSZ  = LW * LH;       // 1360
constexpr int LPAD = 1408;          // 22 chunks * 64 lanes (pad region absorbs clamped lanes)

#define GLOAD_LDS(g, l) __builtin_amdgcn_global_load_lds(                          \
    (const __attribute__((address_space(1))) unsigned int*)(g),                    \
    (__attribute__((address_space(3))) unsigned int*)(l), 4, 0, 0)

__device__ __forceinline__ void stage(const float* __restrict__ xb,
                                      const float* __restrict__ yb,
                                      float* dX, float* dY,
                                      int h0, int w0, int tid, bool interior) {
    if (interior) {
        const int lane = tid & 63;
        const int wv   = tid >> 6;                       // wave id 0..3 (uniform per wave)
        const float* gx = xb + (h0 - HALO) * W + (w0 - HALO);
        const float* gy = yb + (h0 - HALO) * W + (w0 - HALO);
        #pragma unroll
        for (int k = 0; k < 6; ++k) {
            const int j = wv + 4 * k;                    // chunk id, wave-uniform
            if (j < 22) {
                int i = j * 64 + lane;                   // flat LDS index this lane fills
                if (i > LSZ - 1) i = LSZ - 1;            // clamp addr; lands in pad region
                const int l = i / LW;
                const int m = i - l * LW;
                const float* g = gx + l * W + m;
                GLOAD_LDS(g,                  dX + j * 64);
                GLOAD_LDS(gy + (g - gx),      dY + j * 64);
            }
        }
    } else {
        for (int i = tid; i < LSZ; i += 256) {
            const int l  = i / LW;
            const int m  = i - l * LW;
            const int gr = h0 + l - HALO;
            const int gc = w0 + m - HALO;
            const bool ok = ((unsigned)gr < (unsigned)H) && ((unsigned)gc < (unsigned)W);
            const int gi = gr * W + gc;
            dX[i] = ok ? xb[gi] : 0.f;
            dY[i] = ok ? yb[gi] : 0.f;
        }
    }
}

__global__ __launch_bounds__(256, 4)
void zncc_kernel(const float* __restrict__ x,
                 const float* __restrict__ y,
                 float* __restrict__ out) {
    __shared__ float sx[2][LPAD];
    __shared__ float sy[2][LPAD];

    const int tid = threadIdx.x;
    const int tx  = tid & 15;    // 16 thread-cols x 4 px = 64 cols
    const int ty  = tid >> 4;    // 16 rows
    const int w0  = blockIdx.x * TW;
    const int h0  = blockIdx.y * TH;
    const int b   = blockIdx.z;
    const bool interior = (blockIdx.x > 0) && (blockIdx.x < gridDim.x - 1) &&
                          (blockIdx.y > 0) && (blockIdx.y < gridDim.y - 1);

    const float EPS = 1e-4f;
    float chan_acc[4] = {0.f, 0.f, 0.f, 0.f};

    // stage channel 0 into buffer 0
    stage(x + (size_t)(b * C) * (H * W), y + (size_t)(b * C) * (H * W),
          &sx[0][0], &sy[0][0], h0, w0, tid, interior);
    __syncthreads();

    int buf = 0;
    for (int c = 0; c < C; ++c) {
        // issue next channel's staging into the other buffer (hides HBM latency)
        if (c + 1 < C) {
            stage(x + (size_t)(b * C + c + 1) * (H * W),
                  y + (size_t)(b * C + c + 1) * (H * W),
                  &sx[buf ^ 1][0], &sy[buf ^ 1][0], h0, w0, tid, interior);
        }

        const float* bx = &sx[buf][0];
        const float* by = &sy[buf][0];

        // ---- single LDS read pass into registers ----
        float rx[5][8], ry[5][8];
        #pragma unroll
        for (int r = 0; r < 5; ++r) {
            const float4 a0 = *reinterpret_cast<const float4*>(&bx[(ty + r) * LW + 4 * tx]);
            const float4 a1 = *reinterpret_cast<const float4*>(&bx[(ty + r) * LW + 4 * tx + 4]);
            const float4 c0 = *reinterpret_cast<const float4*>(&by[(ty + r) * LW + 4 * tx]);
            const float4 c1 = *reinterpret_cast<const float4*>(&by[(ty + r) * LW + 4 * tx + 4]);
            rx[r][0] = a0.x; rx[r][1] = a0.y; rx[r][2] = a0.z; rx[r][3] = a0.w;
            rx[r][4] = a1.x; rx[r][5] = a1.y; rx[r][6] = a1.z; rx[r][7] = a1.w;
            ry[r][0] = c0.x; ry[r][1] = c0.y; ry[r][2] = c0.z; ry[r][3] = c0.w;
            ry[r][4] = c1.x; ry[r][5] = c1.y; ry[r][6] = c1.z; ry[r][7] = c1.w;
        }

        // ---- 5x5 means via sliding row sums (from regs) ----
        float sxs[4] = {0.f, 0.f, 0.f, 0.f};
        float sys[4] = {0.f, 0.f, 0.f, 0.f};
        #pragma unroll
        for (int r = 0; r < 5; ++r) {
            float s = rx[r][0] + rx[r][1] + rx[r][2] + rx[r][3] + rx[r][4];
            sxs[0] += s; s += rx[r][5] - rx[r][0];
            sxs[1] += s; s += rx[r][6] - rx[r][1];
            sxs[2] += s; s += rx[r][7] - rx[r][2];
            sxs[3] += s;
            float t = ry[r][0] + ry[r][1] + ry[r][2] + ry[r][3] + ry[r][4];
            sys[0] += t; t += ry[r][5] - ry[r][0];
            sys[1] += t; t += ry[r][6] - ry[r][1];
            sys[2] += t; t += ry[r][7] - ry[r][2];
            sys[3] += t;
        }
        float mx[4], my[4];
        #pragma unroll
        for (int p = 0; p < 4; ++p) {
            mx[p] = sxs[p] * (1.f / 25.f);
            my[p] = sys[p] * (1.f / 25.f);
        }

        // ---- ncc accumulation (from regs) ----
        float acc[4] = {0.f, 0.f, 0.f, 0.f};
        #pragma unroll
        for (int r = 0; r < 5; ++r) {
            #pragma unroll
            for (int p = 0; p < 4; ++p) {
                #pragma unroll
                for (int j = 0; j < 5; ++j) {
                    const float dx  = rx[r][p + j] - mx[p];
                    const float dy  = ry[r][p + j] - my[p];
                    const float num = fabsf(dx * dy) + EPS;       // |dx|*|dy| == |dx*dy|
                    const float den = (dx * dx + EPS) * (dy * dy + EPS);
                    acc[p] += num * __builtin_amdgcn_rsqf(den);
                }
            }
        }
        #pragma unroll
        for (int p = 0; p < 4; ++p) {
            float v = acc[p] * (1.f / 25.f);
            v = fminf(fmaxf(v, 0.f), 1.f);
            chan_acc[p] += v;
        }

        __syncthreads();   // staged c+1 complete; everyone done reading buf
        buf ^= 1;
    }

    const int orow = h0 + ty;
    float4 o;
    o.x = chan_acc[0] * (1.f / 3.f);
    o.y = chan_acc[1] * (1.f / 3.f);
    o.z = chan_acc[2] * (1.f / 3.f);
    o.w = chan_acc[3] * (1.f / 3.f);
    *reinterpret_cast<float4*>(&out[((size_t)b * H + orow) * W + w0 + 4 * tx]) = o;
}

extern "C" void kernel_launch(void* const* d_in, const int* in_sizes, int n_in,
                              void* d_out, int out_size, void* d_ws, size_t ws_size,
                              hipStream_t stream) {
    const float* x = (const float*)d_in[0];
    const float* y = (const float*)d_in[1];
    float* out = (float*)d_out;
    dim3 grid(W / TW, H / TH, NB);   // 8, 32, 4 = 1024 blocks
    zncc_kernel<<<grid, dim3(256), 0, stream>>>(x, y, out);
}

// Round 3
// 56.854 us; speedup vs baseline: 1.1531x; 1.1531x over previous
//
#include <hip/hip_runtime.h>

// ZNCC 5x5, zero-padded, count_include_pad means.
// x,y: (4,3,512,512) f32 -> out: (4,1,512,512) f32
// Round 3: round-1 two-pass structure (no reg-cache spill), but 2 px/thread
// with 64x8 tiles -> 2048 blocks -> 32 waves/CU occupancy ceiling (was 16).

constexpr int W  = 512, H = 512, C = 3, NB = 4;
constexpr int TW = 64, TH = 8, HALO = 2;
constexpr int LW = TW + 2 * HALO;   // 68 floats/row (even -> float2 alignment kept)
constexpr int LH = TH + 2 * HALO;   // 12
constexpr int LSZ = LW * LH;        // 816

__global__ __launch_bounds__(256, 8)
void zncc_kernel(const float* __restrict__ x,
                 const float* __restrict__ y,
                 float* __restrict__ out) {
    __shared__ float sx[LSZ];
    __shared__ float sy[LSZ];

    const int tid = threadIdx.x;
    const int tx  = tid & 31;    // 32 thread-cols x 2 px = 64 cols
    const int ty  = tid >> 5;    // 8 rows
    const int w0  = blockIdx.x * TW;
    const int h0  = blockIdx.y * TH;
    const int b   = blockIdx.z;

    const float EPS = 1e-4f;
    float chan_acc[2] = {0.f, 0.f};

    for (int c = 0; c < C; ++c) {
        const float* __restrict__ xb = x + (size_t)(b * C + c) * (H * W);
        const float* __restrict__ yb = y + (size_t)(b * C + c) * (H * W);

        // ---- stage zero-padded 12x68 tiles ----
        for (int i = tid; i < LSZ; i += 256) {
            const int l  = i / LW;
            const int m  = i - l * LW;
            const int gr = h0 + l - HALO;
            const int gc = w0 + m - HALO;
            const bool ok = ((unsigned)gr < (unsigned)H) && ((unsigned)gc < (unsigned)W);
            const int gi = gr * W + gc;
            sx[i] = ok ? xb[gi] : 0.f;
            sy[i] = ok ? yb[gi] : 0.f;
        }
        __syncthreads();

        // ---- pass A: 5x5 sums for my 2 pixels ----
        float sx0 = 0.f, sx1 = 0.f, sy0 = 0.f, sy1 = 0.f;
        #pragma unroll
        for (int r = 0; r < 5; ++r) {
            const int base = (ty + r) * LW + 2 * tx;
            const float2 a0 = *reinterpret_cast<const float2*>(&sx[base]);
            const float2 a1 = *reinterpret_cast<const float2*>(&sx[base + 2]);
            const float2 a2 = *reinterpret_cast<const float2*>(&sx[base + 4]);
            const float2 b0 = *reinterpret_cast<const float2*>(&sy[base]);
            const float2 b1 = *reinterpret_cast<const float2*>(&sy[base + 2]);
            const float2 b2 = *reinterpret_cast<const float2*>(&sy[base + 4]);
            const float cxm = a0.y + a1.x + a1.y + a2.x;   // shared middle 4
            sx0 += cxm + a0.x;
            sx1 += cxm + a2.y;
            const float cym = b0.y + b1.x + b1.y + b2.x;
            sy0 += cym + b0.x;
            sy1 += cym + b2.y;
        }
        const float mx0 = sx0 * (1.f / 25.f), mx1 = sx1 * (1.f / 25.f);
        const float my0 = sy0 * (1.f / 25.f), my1 = sy1 * (1.f / 25.f);

        // ---- pass B: ncc accumulation ----
        float acc0 = 0.f, acc1 = 0.f;
        #pragma unroll
        for (int r = 0; r < 5; ++r) {
            const int base = (ty + r) * LW + 2 * tx;
            const float2 a0 = *reinterpret_cast<const float2*>(&sx[base]);
            const float2 a1 = *reinterpret_cast<const float2*>(&sx[base + 2]);
            const float2 a2 = *reinterpret_cast<const float2*>(&sx[base + 4]);
            const float2 b0 = *reinterpret_cast<const float2*>(&sy[base]);
            const float2 b1 = *reinterpret_cast<const float2*>(&sy[base + 2]);
            const float2 b2 = *reinterpret_cast<const float2*>(&sy[base + 4]);
            const float cx[6] = {a0.x, a0.y, a1.x, a1.y, a2.x, a2.y};
            const float cy[6] = {b0.x, b0.y, b1.x, b1.y, b2.x, b2.y};
            #pragma unroll
            for (int j = 0; j < 5; ++j) {
                {
                    const float dx  = cx[j] - mx0;
                    const float dy  = cy[j] - my0;
                    const float num = fabsf(dx * dy) + EPS;
                    const float den = (dx * dx + EPS) * (dy * dy + EPS);
                    acc0 += num * __builtin_amdgcn_rsqf(den);
                }
                {
                    const float dx  = cx[j + 1] - mx1;
                    const float dy  = cy[j + 1] - my1;
                    const float num = fabsf(dx * dy) + EPS;
                    const float den = (dx * dx + EPS) * (dy * dy + EPS);
                    acc1 += num * __builtin_amdgcn_rsqf(den);
                }
            }
        }
        {
            float v0 = acc0 * (1.f / 25.f);
            float v1 = acc1 * (1.f / 25.f);
            v0 = fminf(fmaxf(v0, 0.f), 1.f);
            v1 = fminf(fmaxf(v1, 0.f), 1.f);
            chan_acc[0] += v0;
            chan_acc[1] += v1;
        }
        __syncthreads();   // everyone done reading before next channel's staging
    }

    const int orow = h0 + ty;
    float2 o;
    o.x = chan_acc[0] * (1.f / 3.f);
    o.y = chan_acc[1] * (1.f / 3.f);
    *reinterpret_cast<float2*>(&out[((size_t)b * H + orow) * W + w0 + 2 * tx]) = o;
}

extern "C" void kernel_launch(void* const* d_in, const int* in_sizes, int n_in,
                              void* d_out, int out_size, void* d_ws, size_t ws_size,
                              hipStream_t stream) {
    const float* x = (const float*)d_in[0];
    const float* y = (const float*)d_in[1];
    float* out = (float*)d_out;
    dim3 grid(W / TW, H / TH, NB);   // 8, 64, 4 = 2048 blocks (8 per CU)
    zncc_kernel<<<grid, dim3(256), 0, stream>>>(x, y, out);
}